// Round 14
// baseline (785.515 us; speedup 1.0000x reference)
//
#include <hip/hip_runtime.h>
#include <hip/hip_bf16.h>
#include <stdint.h>

typedef __hip_bfloat16 bf16;
typedef __attribute__((ext_vector_type(8))) short short8;
typedef __attribute__((ext_vector_type(4))) float f32x4;
typedef __attribute__((ext_vector_type(4))) float f4v;

#define DIMN 128
#define BM 64
#define EPSLN 1e-5f

__device__ __forceinline__ float sigm(float x) { return 1.0f / (1.0f + __expf(-x)); }

__device__ __forceinline__ float bfb2f(unsigned short u) {
    union { uint32_t i; float f; } v; v.i = ((uint32_t)u) << 16; return v.f;
}
__device__ __forceinline__ unsigned short f2bfb(float f) {
    union { float f; uint32_t i; } v; v.f = f;
    uint32_t x = v.i;
    return (unsigned short)((x + 0x7FFFu + ((x >> 16) & 1u)) >> 16);
}

template<int F32>
__device__ __forceinline__ float ld(const void* p, size_t i) {
    if (F32) return ((const float*)p)[i];
    else     return bfb2f(((const unsigned short*)p)[i]);
}
template<int F32>
__device__ __forceinline__ void st_nt(void* p, size_t i, float v) {
    if (F32) __builtin_nontemporal_store(v, (float*)p + i);
    else     __builtin_nontemporal_store(f2bfb(v), (unsigned short*)p + i);
}
template<int F32>
__device__ __forceinline__ void load8(const void* p, size_t elem, float v[8]) {
    if (F32) {
        const f4v* q = (const f4v*)((const float*)p + elem);
        f4v a = q[0], b = q[1];
        v[0]=a.x; v[1]=a.y; v[2]=a.z; v[3]=a.w;
        v[4]=b.x; v[5]=b.y; v[6]=b.z; v[7]=b.w;
    } else {
        short8 s = *(const short8*)((const short*)p + elem);
#pragma unroll
        for (int j = 0; j < 8; ++j) v[j] = bfb2f((unsigned short)s[j]);
    }
}
template<int F32>
__device__ __forceinline__ void load8_nt(const void* p, size_t elem, float v[8]) {
    if (F32) {
        const f4v* q = (const f4v*)((const float*)p + elem);
        f4v a = __builtin_nontemporal_load(q);
        f4v b = __builtin_nontemporal_load(q + 1);
        v[0]=a.x; v[1]=a.y; v[2]=a.z; v[3]=a.w;
        v[4]=b.x; v[5]=b.y; v[6]=b.z; v[7]=b.w;
    } else {
        short8 s = __builtin_nontemporal_load((const short8*)((const short*)p + elem));
#pragma unroll
        for (int j = 0; j < 8; ++j) v[j] = bfb2f((unsigned short)s[j]);
    }
}

// [64][128] bf16 tile, row stride 256 B, XOR-swizzled 16B units
__device__ __forceinline__ uint32_t taddr(int r, int k) {
    return (uint32_t)(r * 256 + ((k * 2) ^ ((r & 7) << 4)));
}
// node_update X2 tile: [64][256], row stride 512 B
__device__ __forceinline__ uint32_t x2addr(int r, int k) {
    return (uint32_t)(r * 512 + ((k * 2) ^ ((r & 7) << 4)));
}

// packed bf16x2 atomic add (gfx950)
__device__ __forceinline__ void atomic_pk_add_bf16(unsigned short* addr, uint32_t data2) {
    unsigned long long a = (unsigned long long)addr;
    asm volatile("global_atomic_pk_add_bf16 %0, %1, off" : : "v"(a), "v"(data2) : "memory");
}

// ---------------------------------------------------------------------------
// dtype detector
// ---------------------------------------------------------------------------
__global__ void detect_dtype_kernel(const uint32_t* __restrict__ w, int* __restrict__ flag) {
    if (threadIdx.x == 0 && blockIdx.x == 0) {
        int c = 0;
        for (int i = 0; i < 64; ++i) {
            uint32_t lo = w[i] & 0xFFFFu;
            int e = (int)((lo >> 7) & 0xFF);
            if (e >= 90 && e <= 140) ++c;
        }
        *flag = (c < 32) ? 1 : 0;   // 1 => float32 tensors
    }
}

// ---------------------------------------------------------------------------
// weight prep: wT[c][k] = w[k][c]
// ---------------------------------------------------------------------------
template<int F32>
__device__ void prep_body(
    const void* w_eg, const void* w_e1, const void* w_e2,
    const void* w_src, const void* w_dst, const void* w_msg,
    const void* w_n1, const void* w_n2,
    unsigned short* wtg, unsigned short* wt1, unsigned short* wt2,
    unsigned short* wts, unsigned short* wtd, unsigned short* wtm,
    unsigned short* wn1t, unsigned short* wn2t)
{
    int idx = blockIdx.x * 256 + threadIdx.x;
    if (idx < 16384) {
        int c = idx >> 7, k = idx & 127;
        wtg[idx] = f2bfb(ld<F32>(w_eg, (size_t)k * 128 + c));
    } else if (idx < 32768) {
        int i = idx - 16384; int c = i >> 7, k = i & 127;
        wt2[i] = f2bfb(ld<F32>(w_e2, (size_t)k * 128 + c));
    } else if (idx < 81920) {
        int i = idx - 32768; int c = i / 384, k = i % 384;
        wt1[i] = f2bfb(ld<F32>(w_e1, (size_t)k * 128 + c));
    } else if (idx < 98304) {
        int i = idx - 81920; int c = i >> 7, k = i & 127;
        wts[i] = f2bfb(ld<F32>(w_src, (size_t)k * 128 + c));
    } else if (idx < 114688) {
        int i = idx - 98304; int c = i >> 7, k = i & 127;
        wtd[i] = f2bfb(ld<F32>(w_dst, (size_t)k * 128 + c));
    } else if (idx < 131072) {
        int i = idx - 114688; int c = i >> 7, k = i & 127;
        wtm[i] = f2bfb(ld<F32>(w_msg, (size_t)k * 128 + c));
    } else if (idx < 163840) {
        int i = idx - 131072; int c = i >> 8, k = i & 255;
        wn1t[i] = f2bfb(ld<F32>(w_n1, (size_t)k * 128 + c));
    } else if (idx < 180224) {
        int i = idx - 163840; int c = i >> 7, k = i & 127;
        wn2t[i] = f2bfb(ld<F32>(w_n2, (size_t)k * 128 + c));
    }
}
__global__ void __launch_bounds__(256) prep_weights_kernel(
    const int* __restrict__ flag,
    const void* w_eg, const void* w_e1, const void* w_e2,
    const void* w_src, const void* w_dst, const void* w_msg,
    const void* w_n1, const void* w_n2,
    unsigned short* wtg, unsigned short* wt1, unsigned short* wt2,
    unsigned short* wts, unsigned short* wtd, unsigned short* wtm,
    unsigned short* wn1t, unsigned short* wn2t)
{
    if (*flag) prep_body<1>(w_eg, w_e1, w_e2, w_src, w_dst, w_msg, w_n1, w_n2,
                            wtg, wt1, wt2, wts, wtd, wtm, wn1t, wn2t);
    else       prep_body<0>(w_eg, w_e1, w_e2, w_src, w_dst, w_msg, w_n1, w_n2,
                            wtg, wt1, wt2, wts, wtd, wtm, wn1t, wn2t);
}

// ---------------------------------------------------------------------------
// node projections — MFMA + q_b/q_c = p_msg @ w_e1[128:256 / 256:384]
// ---------------------------------------------------------------------------
template<int F32>
__device__ void node_proj_body(
    char* hs,
    const void* h,
    const unsigned short* __restrict__ wts, const unsigned short* __restrict__ wtd,
    const unsigned short* __restrict__ wtm, const unsigned short* __restrict__ wt1,
    const void* b_src, const void* b_dst, const void* b_msg,
    unsigned short* __restrict__ p_src, unsigned short* __restrict__ p_dst,
    unsigned short* __restrict__ p_msg,
    unsigned short* __restrict__ q_b, unsigned short* __restrict__ q_c, int n)
{
    const int tid = threadIdx.x;
    const int base = blockIdx.x * BM;

    for (int idx = tid; idx < BM * 16; idx += 256) {
        int r = idx >> 4, kc = (idx & 15) * 8;
        int row = base + r;
        short8 pk;
        if (row < n) {
            float v[8];
            load8<F32>(h, (size_t)row * 128 + kc, v);
#pragma unroll
            for (int j = 0; j < 8; ++j) pk[j] = (short)f2bfb(v[j]);
        } else {
#pragma unroll
            for (int j = 0; j < 8; ++j) pk[j] = 0;
        }
        *(short8*)(hs + taddr(r, kc)) = pk;
    }
    __syncthreads();

    const int lane = tid & 63;
    const int wv = tid >> 6;
    const int l16 = lane & 15;
    const int lk = lane >> 4;
    const int colbase = wv * 32;

    f32x4 as_[4][2], ad_[4][2], am_[4][2];
#pragma unroll
    for (int mf = 0; mf < 4; ++mf)
#pragma unroll
        for (int nf = 0; nf < 2; ++nf) {
            as_[mf][nf] = (f32x4){0.f,0.f,0.f,0.f};
            ad_[mf][nf] = (f32x4){0.f,0.f,0.f,0.f};
            am_[mf][nf] = (f32x4){0.f,0.f,0.f,0.f};
        }

    for (int kt = 0; kt < 4; ++kt) {
        int k0 = kt * 32;
        short8 a[4];
#pragma unroll
        for (int mf = 0; mf < 4; ++mf)
            a[mf] = *(const short8*)(hs + taddr(mf * 16 + l16, k0 + lk * 8));
        short8 bs0 = *(const short8*)(wts + ((size_t)(colbase + l16)      * 128 + k0 + lk * 8));
        short8 bs1 = *(const short8*)(wts + ((size_t)(colbase + 16 + l16) * 128 + k0 + lk * 8));
        short8 bd0 = *(const short8*)(wtd + ((size_t)(colbase + l16)      * 128 + k0 + lk * 8));
        short8 bd1 = *(const short8*)(wtd + ((size_t)(colbase + 16 + l16) * 128 + k0 + lk * 8));
        short8 bm0 = *(const short8*)(wtm + ((size_t)(colbase + l16)      * 128 + k0 + lk * 8));
        short8 bm1 = *(const short8*)(wtm + ((size_t)(colbase + 16 + l16) * 128 + k0 + lk * 8));
#pragma unroll
        for (int mf = 0; mf < 4; ++mf) {
            as_[mf][0] = __builtin_amdgcn_mfma_f32_16x16x32_bf16(a[mf], bs0, as_[mf][0], 0, 0, 0);
            as_[mf][1] = __builtin_amdgcn_mfma_f32_16x16x32_bf16(a[mf], bs1, as_[mf][1], 0, 0, 0);
            ad_[mf][0] = __builtin_amdgcn_mfma_f32_16x16x32_bf16(a[mf], bd0, ad_[mf][0], 0, 0, 0);
            ad_[mf][1] = __builtin_amdgcn_mfma_f32_16x16x32_bf16(a[mf], bd1, ad_[mf][1], 0, 0, 0);
            am_[mf][0] = __builtin_amdgcn_mfma_f32_16x16x32_bf16(a[mf], bm0, am_[mf][0], 0, 0, 0);
            am_[mf][1] = __builtin_amdgcn_mfma_f32_16x16x32_bf16(a[mf], bm1, am_[mf][1], 0, 0, 0);
        }
    }

    float bsv[2] = { ld<F32>(b_src, colbase + l16), ld<F32>(b_src, colbase + 16 + l16) };
    float bdv[2] = { ld<F32>(b_dst, colbase + l16), ld<F32>(b_dst, colbase + 16 + l16) };
    float bmv[2] = { ld<F32>(b_msg, colbase + l16), ld<F32>(b_msg, colbase + 16 + l16) };
    float pm[4][2][4];
#pragma unroll
    for (int mf = 0; mf < 4; ++mf)
#pragma unroll
        for (int nf = 0; nf < 2; ++nf) {
            int col = colbase + nf * 16 + l16;
#pragma unroll
            for (int rr = 0; rr < 4; ++rr) {
                int row = mf * 16 + lk * 4 + rr;
                float pmv_ = am_[mf][nf][rr] + bmv[nf];
                pm[mf][nf][rr] = pmv_;
                if (base + row < n) {
                    size_t o = (size_t)(base + row) * 128 + col;
                    p_src[o] = f2bfb(as_[mf][nf][rr] + bsv[nf]);
                    p_dst[o] = f2bfb(ad_[mf][nf][rr] + bdv[nf]);
                    p_msg[o] = f2bfb(pmv_);
                }
            }
        }
    __syncthreads();   // all hs reads done

    // overwrite hs with p_msg (bf16, fragment scatter)
#pragma unroll
    for (int mf = 0; mf < 4; ++mf)
#pragma unroll
        for (int nf = 0; nf < 2; ++nf) {
            int col = colbase + nf * 16 + l16;
#pragma unroll
            for (int rr = 0; rr < 4; ++rr) {
                int row = mf * 16 + lk * 4 + rr;
                *(unsigned short*)(hs + taddr(row, col)) = f2bfb(pm[mf][nf][rr]);
            }
        }
    __syncthreads();

    // q_b = p_msg @ W1b, q_c = p_msg @ W1c (no bias)
    f32x4 qb_[4][2], qc_[4][2];
#pragma unroll
    for (int mf = 0; mf < 4; ++mf)
#pragma unroll
        for (int nf = 0; nf < 2; ++nf) {
            qb_[mf][nf] = (f32x4){0.f,0.f,0.f,0.f};
            qc_[mf][nf] = (f32x4){0.f,0.f,0.f,0.f};
        }
    for (int kt = 0; kt < 4; ++kt) {
        int k0 = kt * 32;
        short8 a[4];
#pragma unroll
        for (int mf = 0; mf < 4; ++mf)
            a[mf] = *(const short8*)(hs + taddr(mf * 16 + l16, k0 + lk * 8));
        short8 qb0 = *(const short8*)(wt1 + ((size_t)(colbase + l16)      * 384 + 128 + k0 + lk * 8));
        short8 qb1 = *(const short8*)(wt1 + ((size_t)(colbase + 16 + l16) * 384 + 128 + k0 + lk * 8));
        short8 qc0 = *(const short8*)(wt1 + ((size_t)(colbase + l16)      * 384 + 256 + k0 + lk * 8));
        short8 qc1 = *(const short8*)(wt1 + ((size_t)(colbase + 16 + l16) * 384 + 256 + k0 + lk * 8));
#pragma unroll
        for (int mf = 0; mf < 4; ++mf) {
            qb_[mf][0] = __builtin_amdgcn_mfma_f32_16x16x32_bf16(a[mf], qb0, qb_[mf][0], 0, 0, 0);
            qb_[mf][1] = __builtin_amdgcn_mfma_f32_16x16x32_bf16(a[mf], qb1, qb_[mf][1], 0, 0, 0);
            qc_[mf][0] = __builtin_amdgcn_mfma_f32_16x16x32_bf16(a[mf], qc0, qc_[mf][0], 0, 0, 0);
            qc_[mf][1] = __builtin_amdgcn_mfma_f32_16x16x32_bf16(a[mf], qc1, qc_[mf][1], 0, 0, 0);
        }
    }
#pragma unroll
    for (int mf = 0; mf < 4; ++mf)
#pragma unroll
        for (int nf = 0; nf < 2; ++nf) {
            int col = colbase + nf * 16 + l16;
#pragma unroll
            for (int rr = 0; rr < 4; ++rr) {
                int row = mf * 16 + lk * 4 + rr;
                if (base + row < n) {
                    size_t o = (size_t)(base + row) * 128 + col;
                    q_b[o] = f2bfb(qb_[mf][nf][rr]);
                    q_c[o] = f2bfb(qc_[mf][nf][rr]);
                }
            }
        }
}
__global__ void __launch_bounds__(256, 4) node_proj_kernel(
    const int* __restrict__ flag,
    const void* h,
    const unsigned short* wts, const unsigned short* wtd, const unsigned short* wtm,
    const unsigned short* wt1,
    const void* b_src, const void* b_dst, const void* b_msg,
    unsigned short* p_src, unsigned short* p_dst, unsigned short* p_msg,
    unsigned short* q_b, unsigned short* q_c, int n)
{
    __shared__ short hs_raw[BM * 128];   // 16 KB
    char* hs = (char*)hs_raw;
    if (*flag) node_proj_body<1>(hs, h, wts, wtd, wtm, wt1, b_src, b_dst, b_msg,
                                 p_src, p_dst, p_msg, q_b, q_c, n);
    else       node_proj_body<0>(hs, h, wts, wtd, wtm, wt1, b_src, b_dst, b_msg,
                                 p_src, p_dst, p_msg, q_b, q_c, n);
}

// ---------------------------------------------------------------------------
// fused edge mega-kernel — K=128 mm1, e-only staging, 2×16KB LDS, 4 blocks/CU
// ---------------------------------------------------------------------------
template<int F32>
__device__ void edge_mega_body(
    char* es, char* r2, int* sidx, int* didx,
    float* sm_s, float* sm_s2, float* sm_mu, float* sm_rs,
    float* bge_s, float* be1_s,
    const void* e,
    const int* __restrict__ src, const int* __restrict__ dst,
    const unsigned short* __restrict__ p_src, const unsigned short* __restrict__ p_dst,
    const unsigned short* __restrict__ p_msg,
    const unsigned short* __restrict__ q_b, const unsigned short* __restrict__ q_c,
    const unsigned short* __restrict__ wtg,
    const unsigned short* __restrict__ wt1,
    const unsigned short* __restrict__ wt2,
    const void* b_e2, const void* g_e, const void* bt_e,
    unsigned short* __restrict__ agg, void* out, size_t obase, int ne)
{
    const int tid = threadIdx.x;
    const int base = blockIdx.x * BM;

    if (tid < BM) {
        int eid = base + tid;
        sidx[tid] = (eid < ne) ? src[eid] : 0;
        didx[tid] = (eid < ne) ? dst[eid] : 0;
        sm_s[tid] = 0.f; sm_s2[tid] = 0.f;
    }
    __syncthreads();   // sidx/didx (and entry's bias preload) visible

    // ---- register gathers for the gate (row-parallel: 4 threads/row, 32 cols) ----
    const int gr = tid >> 2, gq = tid & 3;
    const int gc0 = gq * 32;
    short8 psv[4], pdv[4], pmv[4];
    {
        const unsigned short* ps = p_src + (size_t)sidx[gr] * 128 + gc0;
        const unsigned short* pd = p_dst + (size_t)didx[gr] * 128 + gc0;
        const unsigned short* pmp = p_msg + (size_t)sidx[gr] * 128 + gc0;
#pragma unroll
        for (int i = 0; i < 4; ++i) {
            psv[i] = *(const short8*)(ps + 8 * i);
            pdv[i] = *(const short8*)(pd + 8 * i);
            pmv[i] = *(const short8*)(pmp + 8 * i);
        }
    }

    // ---- stage e only (nt) ----
    for (int idx = tid; idx < BM * 16; idx += 256) {
        int r = idx >> 4, kc = (idx & 15) * 8;
        int eid = base + r;
        short8 pk;
        if (eid < ne) {
            float v[8];
            load8_nt<F32>(e, (size_t)eid * 128 + kc, v);
#pragma unroll
            for (int j = 0; j < 8; ++j) pk[j] = (short)f2bfb(v[j]);
        } else {
#pragma unroll
            for (int j = 0; j < 8; ++j) pk[j] = 0;
        }
        *(short8*)(es + taddr(r, kc)) = pk;
    }
    __syncthreads();                                        // S1

    const int lane = tid & 63;
    const int wv = tid >> 6;
    const int l16 = lane & 15;
    const int lk = lane >> 4;
    const int colbase = wv * 32;

    f32x4 acc1[4][2], accg[4][2];
#pragma unroll
    for (int mf = 0; mf < 4; ++mf)
#pragma unroll
        for (int nf = 0; nf < 2; ++nf) {
            acc1[mf][nf] = (f32x4){0.f,0.f,0.f,0.f};
            accg[mf][nf] = (f32x4){0.f,0.f,0.f,0.f};
        }

    // ---- mm1 (K=128): e @ W1a, and gate e @ w_eg ----
    for (int kt = 0; kt < 4; ++kt) {
        int k0 = kt * 32;
        short8 a[4];
#pragma unroll
        for (int mf = 0; mf < 4; ++mf)
            a[mf] = *(const short8*)(es + taddr(mf * 16 + l16, k0 + lk * 8));
        short8 b0 = *(const short8*)(wt1 + ((size_t)(colbase + l16)      * 384 + k0 + lk * 8));
        short8 b1 = *(const short8*)(wt1 + ((size_t)(colbase + 16 + l16) * 384 + k0 + lk * 8));
        short8 g0 = *(const short8*)(wtg + ((size_t)(colbase + l16)      * 128 + k0 + lk * 8));
        short8 g1 = *(const short8*)(wtg + ((size_t)(colbase + 16 + l16) * 128 + k0 + lk * 8));
#pragma unroll
        for (int mf = 0; mf < 4; ++mf) {
            acc1[mf][0] = __builtin_amdgcn_mfma_f32_16x16x32_bf16(a[mf], b0, acc1[mf][0], 0, 0, 0);
            acc1[mf][1] = __builtin_amdgcn_mfma_f32_16x16x32_bf16(a[mf], b1, acc1[mf][1], 0, 0, 0);
            accg[mf][0] = __builtin_amdgcn_mfma_f32_16x16x32_bf16(a[mf], g0, accg[mf][0], 0, 0, 0);
            accg[mf][1] = __builtin_amdgcn_mfma_f32_16x16x32_bf16(a[mf], g1, accg[mf][1], 0, 0, 0);
        }
    }

    // ---- spill accg -> R2 ----
#pragma unroll
    for (int mf = 0; mf < 4; ++mf)
#pragma unroll
        for (int nf = 0; nf < 2; ++nf) {
            int col = colbase + nf * 16 + l16;
#pragma unroll
            for (int rr = 0; rr < 4; ++rr) {
                int row = mf * 16 + lk * 4 + rr;
                *(unsigned short*)(r2 + taddr(row, col)) = f2bfb(accg[mf][nf][rr]);
            }
        }
    __syncthreads();                                        // S3

    // ---- row-parallel gate: m = sigm(accg + bge + ps + pd) * pm, in place ----
    {
        int eid = base + gr;
        if (eid < ne) {
            short8 agv[4];
#pragma unroll
            for (int i = 0; i < 4; ++i)
                agv[i] = *(const short8*)(r2 + taddr(gr, gc0 + 8 * i));
#pragma unroll
            for (int i = 0; i < 4; ++i) {
                short8 mv;
#pragma unroll
                for (int j = 0; j < 8; ++j) {
                    int c = gc0 + 8 * i + j;
                    float g = bfb2f((unsigned short)agv[i][j]) + bge_s[c]
                            + bfb2f((unsigned short)psv[i][j])
                            + bfb2f((unsigned short)pdv[i][j]);
                    float m = sigm(g) * bfb2f((unsigned short)pmv[i][j]);
                    mv[j] = (short)f2bfb(m);
                }
                *(short8*)(r2 + taddr(gr, gc0 + 8 * i)) = mv;
            }
        }
    }
    // issue q_b/q_c gathers now (consumed at silu, after scatter)
    short8 qbv[4], qcv[4];
    {
        const unsigned short* qb = q_b + (size_t)sidx[gr] * 128 + gc0;
        const unsigned short* qc = q_c + (size_t)didx[gr] * 128 + gc0;
#pragma unroll
        for (int i = 0; i < 4; ++i) {
            qbv[i] = *(const short8*)(qb + 8 * i);
            qcv[i] = *(const short8*)(qc + 8 * i);
        }
    }
    __syncthreads();                                        // S4

    // ---- coalesced pk-bf16 atomic scatter (m from R2) ----
    {
        int col2 = (tid & 63) * 2;
        int r0 = (tid >> 6) * 16;
        for (int rr = 0; rr < 16; ++rr) {
            int row = r0 + rr;
            int eid = base + row;
            if (eid < ne) {
                uint32_t m2 = *(const uint32_t*)(r2 + taddr(row, col2));
                atomic_pk_add_bf16(agg + (size_t)didx[row] * 128 + col2, m2);
            }
        }
    }
    __syncthreads();                                        // S5

    // ---- spill acc1 -> R2 (bf16) ----
#pragma unroll
    for (int mf = 0; mf < 4; ++mf)
#pragma unroll
        for (int nf = 0; nf < 2; ++nf) {
            int col = colbase + nf * 16 + l16;
#pragma unroll
            for (int rr = 0; rr < 4; ++rr) {
                int row = mf * 16 + lk * 4 + rr;
                *(unsigned short*)(r2 + taddr(row, col)) = f2bfb(acc1[mf][nf][rr]);
            }
        }
    __syncthreads();                                        // S6

    // ---- row-parallel silu: u = silu(acc1 + q_b[s] + q_c[d] + b_e1), in place ----
    {
        int eid = base + gr;
        if (eid < ne) {
            short8 a1v[4];
#pragma unroll
            for (int i = 0; i < 4; ++i)
                a1v[i] = *(const short8*)(r2 + taddr(gr, gc0 + 8 * i));
#pragma unroll
            for (int i = 0; i < 4; ++i) {
                short8 uv;
#pragma unroll
                for (int j = 0; j < 8; ++j) {
                    int c = gc0 + 8 * i + j;
                    float u = bfb2f((unsigned short)a1v[i][j])
                            + bfb2f((unsigned short)qbv[i][j])
                            + bfb2f((unsigned short)qcv[i][j])
                            + be1_s[c];
                    u = u * sigm(u);
                    uv[j] = (short)f2bfb(u);
                }
                *(short8*)(r2 + taddr(gr, gc0 + 8 * i)) = uv;
            }
        }
    }
    __syncthreads();                                        // S7

    // ---- mm2 (K=128): u @ w_e2 ----
    f32x4 acc2[4][2];
#pragma unroll
    for (int mf = 0; mf < 4; ++mf)
#pragma unroll
        for (int nf = 0; nf < 2; ++nf) acc2[mf][nf] = (f32x4){0.f,0.f,0.f,0.f};

    for (int kt = 0; kt < 4; ++kt) {
        int k0 = kt * 32;
        short8 a[4];
#pragma unroll
        for (int mf = 0; mf < 4; ++mf)
            a[mf] = *(const short8*)(r2 + taddr(mf * 16 + l16, k0 + lk * 8));
        short8 b0 = *(const short8*)(wt2 + ((size_t)(colbase + l16)      * 128 + k0 + lk * 8));
        short8 b1 = *(const short8*)(wt2 + ((size_t)(colbase + 16 + l16) * 128 + k0 + lk * 8));
#pragma unroll
        for (int mf = 0; mf < 4; ++mf) {
            acc2[mf][0] = __builtin_amdgcn_mfma_f32_16x16x32_bf16(a[mf], b0, acc2[mf][0], 0, 0, 0);
            acc2[mf][1] = __builtin_amdgcn_mfma_f32_16x16x32_bf16(a[mf], b1, acc2[mf][1], 0, 0, 0);
        }
    }

    // ---- residual + LN ----
    float xv[4][2][4];
    {
        float be2[2] = { ld<F32>(b_e2, colbase + l16), ld<F32>(b_e2, colbase + 16 + l16) };
#pragma unroll
        for (int mf = 0; mf < 4; ++mf)
#pragma unroll
            for (int nf = 0; nf < 2; ++nf) {
                int col = colbase + nf * 16 + l16;
#pragma unroll
                for (int rr = 0; rr < 4; ++rr) {
                    int row = mf * 16 + lk * 4 + rr;
                    unsigned short eb = *(const unsigned short*)(es + taddr(row, col));
                    xv[mf][nf][rr] = bfb2f(eb) + acc2[mf][nf][rr] + be2[nf];
                }
            }
    }
#pragma unroll
    for (int mf = 0; mf < 4; ++mf)
#pragma unroll
        for (int rr = 0; rr < 4; ++rr) {
            float v0 = xv[mf][0][rr], v1 = xv[mf][1][rr];
            float s = v0 + v1;
            float s2 = v0 * v0 + v1 * v1;
#pragma unroll
            for (int off = 1; off < 16; off <<= 1) {
                s  += __shfl_xor(s, off, 16);
                s2 += __shfl_xor(s2, off, 16);
            }
            if (l16 == 0) {
                int row = mf * 16 + lk * 4 + rr;
                atomicAdd(&sm_s[row], s);
                atomicAdd(&sm_s2[row], s2);
            }
        }
    __syncthreads();                                        // S8
    if (tid < BM) {
        float mu = sm_s[tid] * (1.f / 128.f);
        float var = sm_s2[tid] * (1.f / 128.f) - mu * mu;
        sm_mu[tid] = mu;
        sm_rs[tid] = rsqrtf(var + EPSLN);
    }
    __syncthreads();                                        // S9

    // ---- store e_new (nt) ----
    {
        float ge[2]  = { ld<F32>(g_e, colbase + l16),  ld<F32>(g_e, colbase + 16 + l16) };
        float bte[2] = { ld<F32>(bt_e, colbase + l16), ld<F32>(bt_e, colbase + 16 + l16) };
#pragma unroll
        for (int mf = 0; mf < 4; ++mf)
#pragma unroll
            for (int nf = 0; nf < 2; ++nf) {
                int col = colbase + nf * 16 + l16;
#pragma unroll
                for (int rr = 0; rr < 4; ++rr) {
                    int row = mf * 16 + lk * 4 + rr;
                    int eid = base + row;
                    float o = (xv[mf][nf][rr] - sm_mu[row]) * sm_rs[row] * ge[nf] + bte[nf];
                    if (eid < ne) st_nt<F32>(out, obase + (size_t)eid * 128 + col, o);
                }
            }
    }
}

template<int F32>
__device__ void edge_mega_entry(
    char* es, char* r2, int* sidx, int* didx,
    float* sm_s, float* sm_s2, float* sm_mu, float* sm_rs,
    float* bge_s, float* be1_s,
    const void* e, const int* src, const int* dst,
    const unsigned short* p_src, const unsigned short* p_dst, const unsigned short* p_msg,
    const unsigned short* q_b, const unsigned short* q_c,
    const unsigned short* wtg, const unsigned short* wt1, const unsigned short* wt2,
    const void* b_eg, const void* b_e1, const void* b_e2,
    const void* g_e, const void* bt_e,
    unsigned short* agg, void* out, size_t obase, int ne)
{
    // preload biases before body (body's first barrier covers visibility)
    int tid = threadIdx.x;
    if (tid >= 128 && tid < 256) {
        bge_s[tid - 128] = ld<F32>(b_eg, tid - 128);
        be1_s[tid - 128] = ld<F32>(b_e1, tid - 128);
    }
    edge_mega_body<F32>(es, r2, sidx, didx, sm_s, sm_s2, sm_mu, sm_rs, bge_s, be1_s,
                        e, src, dst, p_src, p_dst, p_msg, q_b, q_c, wtg, wt1, wt2,
                        b_e2, g_e, bt_e, agg, out, obase, ne);
}

__global__ void __launch_bounds__(256, 4) edge_mega_kernel(
    const int* __restrict__ flag,
    const void* e, const int* src, const int* dst,
    const unsigned short* p_src, const unsigned short* p_dst, const unsigned short* p_msg,
    const unsigned short* q_b, const unsigned short* q_c,
    const unsigned short* wtg, const unsigned short* wt1, const unsigned short* wt2,
    const void* b_eg, const void* b_e1, const void* b_e2,
    const void* g_e, const void* bt_e,
    unsigned short* agg, void* out, size_t obase, int ne)
{
    __shared__ short es_raw[BM * 128];   // 16 KB
    __shared__ short r2_raw[BM * 128];   // 16 KB
    __shared__ int sidx[BM], didx[BM];
    __shared__ float sm_s[BM], sm_s2[BM], sm_mu[BM], sm_rs[BM];
    __shared__ float bge_s[128], be1_s[128];
    char* es = (char*)es_raw;
    char* r2 = (char*)r2_raw;
    if (*flag) edge_mega_entry<1>(es, r2, sidx, didx, sm_s, sm_s2, sm_mu, sm_rs, bge_s, be1_s,
                                  e, src, dst, p_src, p_dst, p_msg, q_b, q_c, wtg, wt1, wt2,
                                  b_eg, b_e1, b_e2, g_e, bt_e, agg, out, obase, ne);
    else       edge_mega_entry<0>(es, r2, sidx, didx, sm_s, sm_s2, sm_mu, sm_rs, bge_s, be1_s,
                                  e, src, dst, p_src, p_dst, p_msg, q_b, q_c, wtg, wt1, wt2,
                                  b_eg, b_e1, b_e2, g_e, bt_e, agg, out, obase, ne);
}

// ---------------------------------------------------------------------------
// node update — MFMA; agg bf16 (unchanged)
// ---------------------------------------------------------------------------
template<int F32>
__device__ void node_update_body(
    char* xs, float* sm_s, float* sm_s2, float* sm_mu, float* sm_rs,
    const void* h, const unsigned short* __restrict__ agg,
    const unsigned short* __restrict__ wn1t, const unsigned short* __restrict__ wn2t,
    const void* b_n1, const void* b_n2,
    const void* g_n, const void* bt_n, void* out, int n)
{
    const int tid = threadIdx.x;
    const int base = blockIdx.x * BM;

    if (tid < BM) { sm_s[tid] = 0.f; sm_s2[tid] = 0.f; }

    for (int idx = tid; idx < BM * 32; idx += 256) {
        int r = idx >> 5, kc = (idx & 31) * 8;
        int row = base + r;
        short8 pk;
        if (row < n) {
            if (kc < 128) {
                float v[8];
                load8<F32>(h, (size_t)row * 128 + kc, v);
#pragma unroll
                for (int j = 0; j < 8; ++j) pk[j] = (short)f2bfb(v[j]);
            } else {
                pk = *(const short8*)(agg + (size_t)row * 128 + (kc - 128));
            }
        } else {
#pragma unroll
            for (int j = 0; j < 8; ++j) pk[j] = 0;
        }
        *(short8*)(xs + x2addr(r, kc)) = pk;
    }
    __syncthreads();

    const int lane = tid & 63;
    const int wv = tid >> 6;
    const int l16 = lane & 15;
    const int lk = lane >> 4;
    const int colbase = wv * 32;

    f32x4 acc1[4][2];
#pragma unroll
    for (int mf = 0; mf < 4; ++mf)
#pragma unroll
        for (int nf = 0; nf < 2; ++nf) acc1[mf][nf] = (f32x4){0.f,0.f,0.f,0.f};

    for (int kt = 0; kt < 8; ++kt) {
        int k0 = kt * 32;
        short8 a[4];
#pragma unroll
        for (int mf = 0; mf < 4; ++mf)
            a[mf] = *(const short8*)(xs + x2addr(mf * 16 + l16, k0 + lk * 8));
        short8 b0 = *(const short8*)(wn1t + ((size_t)(colbase + l16)      * 256 + k0 + lk * 8));
        short8 b1 = *(const short8*)(wn1t + ((size_t)(colbase + 16 + l16) * 256 + k0 + lk * 8));
#pragma unroll
        for (int mf = 0; mf < 4; ++mf) {
            acc1[mf][0] = __builtin_amdgcn_mfma_f32_16x16x32_bf16(a[mf], b0, acc1[mf][0], 0, 0, 0);
            acc1[mf][1] = __builtin_amdgcn_mfma_f32_16x16x32_bf16(a[mf], b1, acc1[mf][1], 0, 0, 0);
        }
    }
    __syncthreads();

    {
        float b1v[2] = { ld<F32>(b_n1, colbase + l16), ld<F32>(b_n1, colbase + 16 + l16) };
#pragma unroll
        for (int mf = 0; mf < 4; ++mf)
#pragma unroll
            for (int nf = 0; nf < 2; ++nf) {
                int col = colbase + nf * 16 + l16;
#pragma unroll
                for (int rr = 0; rr < 4; ++rr) {
                    int row = mf * 16 + lk * 4 + rr;
                    float u = acc1[mf][nf][rr] + b1v[nf];
                    u = u * sigm(u);
                    *(unsigned short*)(xs + x2addr(row, 128 + col)) = f2bfb(u);
                }
            }
    }
    __syncthreads();

    f32x4 acc2[4][2];
#pragma unroll
    for (int mf = 0; mf < 4; ++mf)
#pragma unroll
        for (int nf = 0; nf < 2; ++nf) acc2[mf][nf] = (f32x4){0.f,0.f,0.f,0.f};

    for (int kt = 0; kt < 4; ++kt) {
        int k0 = kt * 32;
        short8 a[4];
#pragma unroll
        for (int mf = 0; mf < 4; ++mf)
            a[mf] = *(const short8*)(xs + x2addr(mf * 16 + l16, 128 + k0 + lk * 8));
        short8 b0 = *(const short8*)(wn2t + ((size_t)(colbase + l16)      * 128 + k0 + lk * 8));
        short8 b1 = *(const short8*)(wn2t + ((size_t)(colbase + 16 + l16) * 128 + k0 + lk * 8));
#pragma unroll
        for (int mf = 0; mf < 4; ++mf) {
            acc2[mf][0] = __builtin_amdgcn_mfma_f32_16x16x32_bf16(a[mf], b0, acc2[mf][0], 0, 0, 0);
            acc2[mf][1] = __builtin_amdgcn_mfma_f32_16x16x32_bf16(a[mf], b1, acc2[mf][1], 0, 0, 0);
        }
    }

    float xv[4][2][4];
    {
        float b2v[2] = { ld<F32>(b_n2, colbase + l16), ld<F32>(b_n2, colbase + 16 + l16) };
#pragma unroll
        for (int mf = 0; mf < 4; ++mf)
#pragma unroll
            for (int nf = 0; nf < 2; ++nf) {
                int col = colbase + nf * 16 + l16;
#pragma unroll
                for (int rr = 0; rr < 4; ++rr) {
                    int row = mf * 16 + lk * 4 + rr;
                    unsigned short hb = *(const unsigned short*)(xs + x2addr(row, col));
                    xv[mf][nf][rr] = bfb2f(hb) + acc2[mf][nf][rr] + b2v[nf];
                }
            }
    }
#pragma unroll
    for (int mf = 0; mf < 4; ++mf)
#pragma unroll
        for (int rr = 0; rr < 4; ++rr) {
            float v0 = xv[mf][0][rr], v1 = xv[mf][1][rr];
            float s = v0 + v1;
            float s2 = v0 * v0 + v1 * v1;
#pragma unroll
            for (int off = 1; off < 16; off <<= 1) {
                s  += __shfl_xor(s, off, 16);
                s2 += __shfl_xor(s2, off, 16);
            }
            if (l16 == 0) {
                int row = mf * 16 + lk * 4 + rr;
                atomicAdd(&sm_s[row], s);
                atomicAdd(&sm_s2[row], s2);
            }
        }
    __syncthreads();
    if (tid < BM) {
        float mu = sm_s[tid] * (1.f / 128.f);
        float var = sm_s2[tid] * (1.f / 128.f) - mu * mu;
        sm_mu[tid] = mu;
        sm_rs[tid] = rsqrtf(var + EPSLN);
    }
    __syncthreads();
    {
        float gn[2]  = { ld<F32>(g_n, colbase + l16),  ld<F32>(g_n, colbase + 16 + l16) };
        float btn[2] = { ld<F32>(bt_n, colbase + l16), ld<F32>(bt_n, colbase + 16 + l16) };
#pragma unroll
        for (int mf = 0; mf < 4; ++mf)
#pragma unroll
            for (int nf = 0; nf < 2; ++nf) {
                int col = colbase + nf * 16 + l16;
#pragma unroll
                for (int rr = 0; rr < 4; ++rr) {
                    int row = mf * 16 + lk * 4 + rr;
                    float o = (xv[mf][nf][rr] - sm_mu[row]) * sm_rs[row] * gn[nf] + btn[nf];
                    if (base + row < n)
                        st_nt<F32>(out, (size_t)(base + row) * 128 + col, o);
                }
            }
    }
}
__global__ void __launch_bounds__(256, 4) node_update_kernel(
    const int* __restrict__ flag,
    const void* h, const unsigned short* agg,
    const unsigned short* wn1t, const unsigned short* wn2t,
    const void* b_n1, const void* b_n2,
    const void* g_n, const void* bt_n, void* out, int n)
{
    __shared__ short x2_raw[BM * 256];   // 32 KB
    __shared__ float sm_s[BM], sm_s2[BM], sm_mu[BM], sm_rs[BM];
    char* xs = (char*)x2_raw;
    if (*flag) node_update_body<1>(xs, sm_s, sm_s2, sm_mu, sm_rs, h, agg, wn1t, wn2t,
                                   b_n1, b_n2, g_n, bt_n, out, n);
    else       node_update_body<0>(xs, sm_s, sm_s2, sm_mu, sm_rs, h, agg, wn1t, wn2t,
                                   b_n1, b_n2, g_n, bt_n, out, n);
}

// ---------------------------------------------------------------------------
extern "C" void kernel_launch(void* const* d_in, const int* in_sizes, int n_in,
                              void* d_out, int out_size, void* d_ws, size_t ws_size,
                              hipStream_t stream)
{
    const void* h     = d_in[0];
    const void* e     = d_in[1];
    const int*  src   = (const int*)d_in[2];
    const int*  dst   = (const int*)d_in[3];
    const void* w_src = d_in[4];
    const void* b_src = d_in[5];
    const void* w_dst = d_in[6];
    const void* b_dst = d_in[7];
    const void* w_eg  = d_in[8];
    const void* b_eg  = d_in[9];
    const void* w_msg = d_in[10];
    const void* b_msg = d_in[11];
    const void* w_n1  = d_in[12];
    const void* b_n1  = d_in[13];
    const void* w_n2  = d_in[14];
    const void* b_n2  = d_in[15];
    const void* w_e1  = d_in[16];
    const void* b_e1  = d_in[17];
    const void* w_e2  = d_in[18];
    const void* b_e2  = d_in[19];
    const void* g_n   = d_in[20];
    const void* bt_n  = d_in[21];
    const void* g_e   = d_in[22];
    const void* bt_e  = d_in[23];

    const int n  = in_sizes[0] / DIMN;   // 40000
    const int ne = in_sizes[1] / DIMN;   // 640000

    char* ws = (char*)d_ws;
    unsigned short* p_src = (unsigned short*)ws;       ws += (size_t)n * DIMN * 2;
    unsigned short* p_dst = (unsigned short*)ws;       ws += (size_t)n * DIMN * 2;
    unsigned short* p_msg = (unsigned short*)ws;       ws += (size_t)n * DIMN * 2;
    unsigned short* q_b   = (unsigned short*)ws;       ws += (size_t)n * DIMN * 2;
    unsigned short* q_c   = (unsigned short*)ws;       ws += (size_t)n * DIMN * 2;
    unsigned short* agg   = (unsigned short*)ws;       ws += (size_t)n * DIMN * 2;
    int*   flag  = (int*)ws;                           ws += 256;
    unsigned short* wtg  = (unsigned short*)ws;        ws += 128 * 128 * 2;
    unsigned short* wt2  = (unsigned short*)ws;        ws += 128 * 128 * 2;
    unsigned short* wt1  = (unsigned short*)ws;        ws += 128 * 384 * 2;
    unsigned short* wts  = (unsigned short*)ws;        ws += 128 * 128 * 2;
    unsigned short* wtd  = (unsigned short*)ws;        ws += 128 * 128 * 2;
    unsigned short* wtm  = (unsigned short*)ws;        ws += 128 * 128 * 2;
    unsigned short* wn1t = (unsigned short*)ws;        ws += 128 * 256 * 2;
    unsigned short* wn2t = (unsigned short*)ws;        ws += 128 * 128 * 2;

    hipMemsetAsync(agg, 0, (size_t)n * DIMN * sizeof(unsigned short), stream);

    detect_dtype_kernel<<<1, 64, 0, stream>>>((const uint32_t*)h, flag);

    prep_weights_kernel<<<704, 256, 0, stream>>>(
        flag, w_eg, w_e1, w_e2, w_src, w_dst, w_msg, w_n1, w_n2,
        wtg, wt1, wt2, wts, wtd, wtm, wn1t, wn2t);

    int nb_n = (n + BM - 1) / BM;
    int nb_e = (ne + BM - 1) / BM;

    node_proj_kernel<<<nb_n, 256, 0, stream>>>(
        flag, h, wts, wtd, wtm, wt1, b_src, b_dst, b_msg,
        p_src, p_dst, p_msg, q_b, q_c, n);

    edge_mega_kernel<<<nb_e, 256, 0, stream>>>(
        flag, e, src, dst, p_src, p_dst, p_msg, q_b, q_c, wtg, wt1, wt2,
        b_eg, b_e1, b_e2, g_e, bt_e, agg, d_out, (size_t)n * DIMN, ne);

    node_update_kernel<<<nb_n, 256, 0, stream>>>(
        flag, h, agg, wn1t, wn2t, b_n1, b_n2, g_n, bt_n, d_out, n);
}

// Round 15
// 700.674 us; speedup vs baseline: 1.1211x; 1.1211x over previous
//
#include <hip/hip_runtime.h>
#include <hip/hip_bf16.h>
#include <stdint.h>

typedef __hip_bfloat16 bf16;
typedef __attribute__((ext_vector_type(8))) short short8;
typedef __attribute__((ext_vector_type(4))) float f32x4;
typedef __attribute__((ext_vector_type(4))) float f4v;   // ext-vector float4 (nontemporal-compatible)

#define DIMN 128
#define BM 64
#define EPSLN 1e-5f

__device__ __forceinline__ float sigm(float x) { return 1.0f / (1.0f + __expf(-x)); }

__device__ __forceinline__ float bfb2f(unsigned short u) {
    union { uint32_t i; float f; } v; v.i = ((uint32_t)u) << 16; return v.f;
}
__device__ __forceinline__ unsigned short f2bfb(float f) {
    union { float f; uint32_t i; } v; v.f = f;
    uint32_t x = v.i;
    return (unsigned short)((x + 0x7FFFu + ((x >> 16) & 1u)) >> 16);
}

template<int F32>
__device__ __forceinline__ float ld(const void* p, size_t i) {
    if (F32) return ((const float*)p)[i];
    else     return bfb2f(((const unsigned short*)p)[i]);
}
template<int F32>
__device__ __forceinline__ void st(void* p, size_t i, float v) {
    if (F32) ((float*)p)[i] = v;
    else     ((unsigned short*)p)[i] = f2bfb(v);
}
// non-temporal store for streamed outputs (keeps L2 for gather/atomic data)
template<int F32>
__device__ __forceinline__ void st_nt(void* p, size_t i, float v) {
    if (F32) __builtin_nontemporal_store(v, (float*)p + i);
    else     __builtin_nontemporal_store(f2bfb(v), (unsigned short*)p + i);
}
template<int F32>
__device__ __forceinline__ void load8(const void* p, size_t elem, float v[8]) {
    if (F32) {
        const f4v* q = (const f4v*)((const float*)p + elem);
        f4v a = q[0], b = q[1];
        v[0]=a.x; v[1]=a.y; v[2]=a.z; v[3]=a.w;
        v[4]=b.x; v[5]=b.y; v[6]=b.z; v[7]=b.w;
    } else {
        short8 s = *(const short8*)((const short*)p + elem);
#pragma unroll
        for (int j = 0; j < 8; ++j) v[j] = bfb2f((unsigned short)s[j]);
    }
}
// non-temporal variant for single-use streaming reads (e)
template<int F32>
__device__ __forceinline__ void load8_nt(const void* p, size_t elem, float v[8]) {
    if (F32) {
        const f4v* q = (const f4v*)((const float*)p + elem);
        f4v a = __builtin_nontemporal_load(q);
        f4v b = __builtin_nontemporal_load(q + 1);
        v[0]=a.x; v[1]=a.y; v[2]=a.z; v[3]=a.w;
        v[4]=b.x; v[5]=b.y; v[6]=b.z; v[7]=b.w;
    } else {
        short8 s = __builtin_nontemporal_load((const short8*)((const short*)p + elem));
#pragma unroll
        for (int j = 0; j < 8; ++j) v[j] = bfb2f((unsigned short)s[j]);
    }
}

// Edge X tile: [64 rows][384 k] bf16, row stride 768 B, XOR-swizzled 16B units
__device__ __forceinline__ uint32_t xaddr(int r, int k) {
    return (uint32_t)(r * 768 + ((k * 2) ^ ((r & 7) << 4)));
}
__device__ __forceinline__ uint32_t uaddr(int r, int k) {
    return (uint32_t)(r * 768 + 512 + ((k * 2) ^ ((r & 7) << 4)));
}
// node_proj h tile: [64][128], row stride 256 B
__device__ __forceinline__ uint32_t haddr(int r, int k) {
    return (uint32_t)(r * 256 + ((k * 2) ^ ((r & 7) << 4)));
}
// node_update X2 tile: [64][256], row stride 512 B
__device__ __forceinline__ uint32_t x2addr(int r, int k) {
    return (uint32_t)(r * 512 + ((k * 2) ^ ((r & 7) << 4)));
}

// packed bf16x2 atomic add (gfx950 global_atomic_pk_add_bf16)
__device__ __forceinline__ void atomic_pk_add_bf16(unsigned short* addr, uint32_t data2) {
    unsigned long long a = (unsigned long long)addr;
    asm volatile("global_atomic_pk_add_bf16 %0, %1, off" : : "v"(a), "v"(data2) : "memory");
}

// ---------------------------------------------------------------------------
// dtype detector
// ---------------------------------------------------------------------------
__global__ void detect_dtype_kernel(const uint32_t* __restrict__ w, int* __restrict__ flag) {
    if (threadIdx.x == 0 && blockIdx.x == 0) {
        int c = 0;
        for (int i = 0; i < 64; ++i) {
            uint32_t lo = w[i] & 0xFFFFu;
            int e = (int)((lo >> 7) & 0xFF);
            if (e >= 90 && e <= 140) ++c;
        }
        *flag = (c < 32) ? 1 : 0;   // 1 => float32 tensors
    }
}

// ---------------------------------------------------------------------------
// weight prep: transpose + bf16-ify all matmul weights  wT[c][k] = w[k][c]
// ---------------------------------------------------------------------------
template<int F32>
__device__ void prep_body(
    const void* w_eg, const void* w_e1, const void* w_e2,
    const void* w_src, const void* w_dst, const void* w_msg,
    const void* w_n1, const void* w_n2,
    unsigned short* wtg, unsigned short* wt1, unsigned short* wt2,
    unsigned short* wts, unsigned short* wtd, unsigned short* wtm,
    unsigned short* wn1t, unsigned short* wn2t)
{
    int idx = blockIdx.x * 256 + threadIdx.x;
    if (idx < 16384) {
        int c = idx >> 7, k = idx & 127;
        wtg[idx] = f2bfb(ld<F32>(w_eg, (size_t)k * 128 + c));
    } else if (idx < 32768) {
        int i = idx - 16384; int c = i >> 7, k = i & 127;
        wt2[i] = f2bfb(ld<F32>(w_e2, (size_t)k * 128 + c));
    } else if (idx < 81920) {
        int i = idx - 32768; int c = i / 384, k = i % 384;
        wt1[i] = f2bfb(ld<F32>(w_e1, (size_t)k * 128 + c));
    } else if (idx < 98304) {
        int i = idx - 81920; int c = i >> 7, k = i & 127;
        wts[i] = f2bfb(ld<F32>(w_src, (size_t)k * 128 + c));
    } else if (idx < 114688) {
        int i = idx - 98304; int c = i >> 7, k = i & 127;
        wtd[i] = f2bfb(ld<F32>(w_dst, (size_t)k * 128 + c));
    } else if (idx < 131072) {
        int i = idx - 114688; int c = i >> 7, k = i & 127;
        wtm[i] = f2bfb(ld<F32>(w_msg, (size_t)k * 128 + c));
    } else if (idx < 163840) {
        int i = idx - 131072; int c = i >> 8, k = i & 255;
        wn1t[i] = f2bfb(ld<F32>(w_n1, (size_t)k * 128 + c));
    } else if (idx < 180224) {
        int i = idx - 163840; int c = i >> 7, k = i & 127;
        wn2t[i] = f2bfb(ld<F32>(w_n2, (size_t)k * 128 + c));
    }
}
__global__ void __launch_bounds__(256) prep_weights_kernel(
    const int* __restrict__ flag,
    const void* w_eg, const void* w_e1, const void* w_e2,
    const void* w_src, const void* w_dst, const void* w_msg,
    const void* w_n1, const void* w_n2,
    unsigned short* wtg, unsigned short* wt1, unsigned short* wt2,
    unsigned short* wts, unsigned short* wtd, unsigned short* wtm,
    unsigned short* wn1t, unsigned short* wn2t)
{
    if (*flag) prep_body<1>(w_eg, w_e1, w_e2, w_src, w_dst, w_msg, w_n1, w_n2,
                            wtg, wt1, wt2, wts, wtd, wtm, wn1t, wn2t);
    else       prep_body<0>(w_eg, w_e1, w_e2, w_src, w_dst, w_msg, w_n1, w_n2,
                            wtg, wt1, wt2, wts, wtd, wtm, wn1t, wn2t);
}

// ---------------------------------------------------------------------------
// node projections — MFMA (known good)
// ---------------------------------------------------------------------------
template<int F32>
__device__ void node_proj_body(
    char* hs,
    const void* h,
    const unsigned short* __restrict__ wts, const unsigned short* __restrict__ wtd,
    const unsigned short* __restrict__ wtm,
    const void* b_src, const void* b_dst, const void* b_msg,
    unsigned short* __restrict__ p_src, unsigned short* __restrict__ p_dst,
    unsigned short* __restrict__ p_msg, int n)
{
    const int tid = threadIdx.x;
    const int base = blockIdx.x * BM;

    for (int idx = tid; idx < BM * 16; idx += 256) {
        int r = idx >> 4, kc = (idx & 15) * 8;
        int row = base + r;
        short8 pk;
        if (row < n) {
            float v[8];
            load8<F32>(h, (size_t)row * 128 + kc, v);
#pragma unroll
            for (int j = 0; j < 8; ++j) pk[j] = (short)f2bfb(v[j]);
        } else {
#pragma unroll
            for (int j = 0; j < 8; ++j) pk[j] = 0;
        }
        *(short8*)(hs + haddr(r, kc)) = pk;
    }
    __syncthreads();

    const int lane = tid & 63;
    const int wv = tid >> 6;
    const int l16 = lane & 15;
    const int lk = lane >> 4;
    const int colbase = wv * 32;

    f32x4 as_[4][2], ad_[4][2], am_[4][2];
#pragma unroll
    for (int mf = 0; mf < 4; ++mf)
#pragma unroll
        for (int nf = 0; nf < 2; ++nf) {
            as_[mf][nf] = (f32x4){0.f,0.f,0.f,0.f};
            ad_[mf][nf] = (f32x4){0.f,0.f,0.f,0.f};
            am_[mf][nf] = (f32x4){0.f,0.f,0.f,0.f};
        }

    for (int kt = 0; kt < 4; ++kt) {
        int k0 = kt * 32;
        short8 a[4];
#pragma unroll
        for (int mf = 0; mf < 4; ++mf)
            a[mf] = *(const short8*)(hs + haddr(mf * 16 + l16, k0 + lk * 8));
        short8 bs0 = *(const short8*)(wts + ((size_t)(colbase + l16)      * 128 + k0 + lk * 8));
        short8 bs1 = *(const short8*)(wts + ((size_t)(colbase + 16 + l16) * 128 + k0 + lk * 8));
        short8 bd0 = *(const short8*)(wtd + ((size_t)(colbase + l16)      * 128 + k0 + lk * 8));
        short8 bd1 = *(const short8*)(wtd + ((size_t)(colbase + 16 + l16) * 128 + k0 + lk * 8));
        short8 bm0 = *(const short8*)(wtm + ((size_t)(colbase + l16)      * 128 + k0 + lk * 8));
        short8 bm1 = *(const short8*)(wtm + ((size_t)(colbase + 16 + l16) * 128 + k0 + lk * 8));
#pragma unroll
        for (int mf = 0; mf < 4; ++mf) {
            as_[mf][0] = __builtin_amdgcn_mfma_f32_16x16x32_bf16(a[mf], bs0, as_[mf][0], 0, 0, 0);
            as_[mf][1] = __builtin_amdgcn_mfma_f32_16x16x32_bf16(a[mf], bs1, as_[mf][1], 0, 0, 0);
            ad_[mf][0] = __builtin_amdgcn_mfma_f32_16x16x32_bf16(a[mf], bd0, ad_[mf][0], 0, 0, 0);
            ad_[mf][1] = __builtin_amdgcn_mfma_f32_16x16x32_bf16(a[mf], bd1, ad_[mf][1], 0, 0, 0);
            am_[mf][0] = __builtin_amdgcn_mfma_f32_16x16x32_bf16(a[mf], bm0, am_[mf][0], 0, 0, 0);
            am_[mf][1] = __builtin_amdgcn_mfma_f32_16x16x32_bf16(a[mf], bm1, am_[mf][1], 0, 0, 0);
        }
    }

    float bsv[2] = { ld<F32>(b_src, colbase + l16), ld<F32>(b_src, colbase + 16 + l16) };
    float bdv[2] = { ld<F32>(b_dst, colbase + l16), ld<F32>(b_dst, colbase + 16 + l16) };
    float bmv[2] = { ld<F32>(b_msg, colbase + l16), ld<F32>(b_msg, colbase + 16 + l16) };
#pragma unroll
    for (int mf = 0; mf < 4; ++mf)
#pragma unroll
        for (int nf = 0; nf < 2; ++nf) {
            int col = colbase + nf * 16 + l16;
#pragma unroll
            for (int rr = 0; rr < 4; ++rr) {
                int row = mf * 16 + lk * 4 + rr;
                if (base + row < n) {
                    size_t o = (size_t)(base + row) * 128 + col;
                    p_src[o] = f2bfb(as_[mf][nf][rr] + bsv[nf]);
                    p_dst[o] = f2bfb(ad_[mf][nf][rr] + bdv[nf]);
                    p_msg[o] = f2bfb(am_[mf][nf][rr] + bmv[nf]);
                }
            }
        }
}
__global__ void __launch_bounds__(256, 4) node_proj_kernel(
    const int* __restrict__ flag,
    const void* h,
    const unsigned short* wts, const unsigned short* wtd, const unsigned short* wtm,
    const void* b_src, const void* b_dst, const void* b_msg,
    unsigned short* p_src, unsigned short* p_dst, unsigned short* p_msg, int n)
{
    __shared__ short hs_raw[BM * 128];   // 16 KB
    char* hs = (char*)hs_raw;
    if (*flag) node_proj_body<1>(hs, h, wts, wtd, wtm, b_src, b_dst, b_msg, p_src, p_dst, p_msg, n);
    else       node_proj_body<0>(hs, h, wts, wtd, wtm, b_src, b_dst, b_msg, p_src, p_dst, p_msg, n);
}

// ---------------------------------------------------------------------------
// fused edge mega-kernel (MFMA) — nt streams for e/e_new, pk-bf16 atomics
// ---------------------------------------------------------------------------
template<int F32>
__device__ void edge_mega_body(
    char* xs, int* sidx, int* didx,
    float* sm_s, float* sm_s2, float* sm_mu, float* sm_rs, float* bge_s,
    const void* e,
    const int* __restrict__ src, const int* __restrict__ dst,
    const unsigned short* __restrict__ p_src, const unsigned short* __restrict__ p_dst,
    const unsigned short* __restrict__ p_msg,
    const unsigned short* __restrict__ wtg,
    const unsigned short* __restrict__ wt1,
    const unsigned short* __restrict__ wt2,
    const void* b_eg, const void* b_e1, const void* b_e2,
    const void* g_e, const void* bt_e,
    unsigned short* __restrict__ agg, void* out, size_t obase, int ne)
{
    const int tid = threadIdx.x;
    const int base = blockIdx.x * BM;

    if (tid < BM) {
        int eid = base + tid;
        sidx[tid] = (eid < ne) ? src[eid] : 0;
        didx[tid] = (eid < ne) ? dst[eid] : 0;
        sm_s[tid] = 0.f; sm_s2[tid] = 0.f;
    }
    if (tid >= 128 && tid < 256) bge_s[tid - 128] = ld<F32>(b_eg, tid - 128);
    __syncthreads();

    // ---- prefetch gate gathers (consumed after mm1) ----
    const int gr = tid >> 2, gq = tid & 3;
    const int gc0 = gq * 32;
    short8 psv[4], pdv[4];
    {
        const unsigned short* ps = p_src + (size_t)sidx[gr] * 128 + gc0;
        const unsigned short* pd = p_dst + (size_t)didx[gr] * 128 + gc0;
#pragma unroll
        for (int i = 0; i < 4; ++i) {
            psv[i] = *(const short8*)(ps + 8 * i);
            pdv[i] = *(const short8*)(pd + 8 * i);
        }
    }

    // ---- stage X = [e | p_msg[src] | p_msg[dst]] as bf16, swizzled ----
    // e is a single-use stream: non-temporal to keep L2 for p_*/agg
    for (int idx = tid; idx < BM * 48; idx += 256) {
        int r = idx / 48;
        int kc = (idx % 48) * 8;
        int eid = base + r;
        short8 pk;
        if (eid < ne) {
            if (kc < 128) {
                float v[8];
                load8_nt<F32>(e, (size_t)eid * 128 + kc, v);
#pragma unroll
                for (int j = 0; j < 8; ++j) pk[j] = (short)f2bfb(v[j]);
            } else if (kc < 256) {
                pk = *(const short8*)(p_msg + (size_t)sidx[r] * 128 + (kc - 128));
            } else {
                pk = *(const short8*)(p_msg + (size_t)didx[r] * 128 + (kc - 256));
            }
        } else {
#pragma unroll
            for (int j = 0; j < 8; ++j) pk[j] = 0;
        }
        *(short8*)(xs + xaddr(r, kc)) = pk;
    }
    __syncthreads();                                        // S1

    const int lane = tid & 63;
    const int wv = tid >> 6;
    const int l16 = lane & 15;
    const int lk = lane >> 4;
    const int colbase = wv * 32;

    f32x4 acc1[4][2], accg[4][2];
#pragma unroll
    for (int mf = 0; mf < 4; ++mf)
#pragma unroll
        for (int nf = 0; nf < 2; ++nf) {
            acc1[mf][nf] = (f32x4){0.f,0.f,0.f,0.f};
            accg[mf][nf] = (f32x4){0.f,0.f,0.f,0.f};
        }

    // ---- matmul1 (K=384) with gate matmul fused into K-steps 0..3 ----
    for (int kt = 0; kt < 12; ++kt) {
        int k0 = kt * 32;
        short8 a[4];
#pragma unroll
        for (int mf = 0; mf < 4; ++mf)
            a[mf] = *(const short8*)(xs + xaddr(mf * 16 + l16, k0 + lk * 8));
        short8 b0 = *(const short8*)(wt1 + ((size_t)(colbase + l16)      * 384 + k0 + lk * 8));
        short8 b1 = *(const short8*)(wt1 + ((size_t)(colbase + 16 + l16) * 384 + k0 + lk * 8));
#pragma unroll
        for (int mf = 0; mf < 4; ++mf) {
            acc1[mf][0] = __builtin_amdgcn_mfma_f32_16x16x32_bf16(a[mf], b0, acc1[mf][0], 0, 0, 0);
            acc1[mf][1] = __builtin_amdgcn_mfma_f32_16x16x32_bf16(a[mf], b1, acc1[mf][1], 0, 0, 0);
        }
        if (kt < 4) {
            short8 g0 = *(const short8*)(wtg + ((size_t)(colbase + l16)      * 128 + k0 + lk * 8));
            short8 g1 = *(const short8*)(wtg + ((size_t)(colbase + 16 + l16) * 128 + k0 + lk * 8));
#pragma unroll
            for (int mf = 0; mf < 4; ++mf) {
                accg[mf][0] = __builtin_amdgcn_mfma_f32_16x16x32_bf16(a[mf], g0, accg[mf][0], 0, 0, 0);
                accg[mf][1] = __builtin_amdgcn_mfma_f32_16x16x32_bf16(a[mf], g1, accg[mf][1], 0, 0, 0);
            }
        }
    }
    __syncthreads();                                        // S2

    // ---- spill accg (bf16) into seg2 ----
#pragma unroll
    for (int mf = 0; mf < 4; ++mf)
#pragma unroll
        for (int nf = 0; nf < 2; ++nf) {
            int col = colbase + nf * 16 + l16;
#pragma unroll
            for (int rr = 0; rr < 4; ++rr) {
                int row = mf * 16 + lk * 4 + rr;
                *(unsigned short*)(xs + uaddr(row, col)) = f2bfb(accg[mf][nf][rr]);
            }
        }
    __syncthreads();                                        // S3

    // ---- row-parallel gate: read pm(seg1)+agv(seg2), write m IN-PLACE to seg1 ----
    {
        int eid = base + gr;
        if (eid < ne) {
            short8 pmv[4], agv[4];
#pragma unroll
            for (int i = 0; i < 4; ++i) {
                pmv[i] = *(const short8*)(xs + xaddr(gr, 128 + gc0 + 8 * i));
                agv[i] = *(const short8*)(xs + uaddr(gr, gc0 + 8 * i));
            }
#pragma unroll
            for (int i = 0; i < 4; ++i) {
                short8 mv;
#pragma unroll
                for (int j = 0; j < 8; ++j) {
                    int c = gc0 + 8 * i + j;
                    float g = bfb2f((unsigned short)agv[i][j]) + bge_s[c]
                            + bfb2f((unsigned short)psv[i][j])
                            + bfb2f((unsigned short)pdv[i][j]);
                    float m = sigm(g) * bfb2f((unsigned short)pmv[i][j]);
                    mv[j] = (short)f2bfb(m);
                }
                *(short8*)(xs + xaddr(gr, 128 + gc0 + 8 * i)) = mv;  // in-place
            }
        }
    }
    __syncthreads();                                        // S4

    // ---- silu, write u into seg2 ----
    {
        float be1[2] = { ld<F32>(b_e1, colbase + l16), ld<F32>(b_e1, colbase + 16 + l16) };
#pragma unroll
        for (int mf = 0; mf < 4; ++mf)
#pragma unroll
            for (int nf = 0; nf < 2; ++nf) {
                int col = colbase + nf * 16 + l16;
#pragma unroll
                for (int rr = 0; rr < 4; ++rr) {
                    int row = mf * 16 + lk * 4 + rr;
                    float u = acc1[mf][nf][rr] + be1[nf];
                    u = u * sigm(u);
                    *(unsigned short*)(xs + uaddr(row, col)) = f2bfb(u);
                }
            }
    }
    __syncthreads();                                        // S5

    // ---- matmul2 (K=128): u @ w_e2 ----
    f32x4 acc2[4][2];
#pragma unroll
    for (int mf = 0; mf < 4; ++mf)
#pragma unroll
        for (int nf = 0; nf < 2; ++nf) acc2[mf][nf] = (f32x4){0.f,0.f,0.f,0.f};

    for (int kt = 0; kt < 4; ++kt) {
        int k0 = kt * 32;
        short8 a[4];
#pragma unroll
        for (int mf = 0; mf < 4; ++mf)
            a[mf] = *(const short8*)(xs + uaddr(mf * 16 + l16, k0 + lk * 8));
        short8 b0 = *(const short8*)(wt2 + ((size_t)(colbase + l16)      * 128 + k0 + lk * 8));
        short8 b1 = *(const short8*)(wt2 + ((size_t)(colbase + 16 + l16) * 128 + k0 + lk * 8));
#pragma unroll
        for (int mf = 0; mf < 4; ++mf) {
            acc2[mf][0] = __builtin_amdgcn_mfma_f32_16x16x32_bf16(a[mf], b0, acc2[mf][0], 0, 0, 0);
            acc2[mf][1] = __builtin_amdgcn_mfma_f32_16x16x32_bf16(a[mf], b1, acc2[mf][1], 0, 0, 0);
        }
    }

    // ---- residual + LN ----
    float xv[4][2][4];
    {
        float be2[2] = { ld<F32>(b_e2, colbase + l16), ld<F32>(b_e2, colbase + 16 + l16) };
#pragma unroll
        for (int mf = 0; mf < 4; ++mf)
#pragma unroll
            for (int nf = 0; nf < 2; ++nf) {
                int col = colbase + nf * 16 + l16;
#pragma unroll
                for (int rr = 0; rr < 4; ++rr) {
                    int row = mf * 16 + lk * 4 + rr;
                    unsigned short eb = *(const unsigned short*)(xs + xaddr(row, col));
                    xv[mf][nf][rr] = bfb2f(eb) + acc2[mf][nf][rr] + be2[nf];
                }
            }
    }
#pragma unroll
    for (int mf = 0; mf < 4; ++mf)
#pragma unroll
        for (int rr = 0; rr < 4; ++rr) {
            float v0 = xv[mf][0][rr], v1 = xv[mf][1][rr];
            float s = v0 + v1;
            float s2 = v0 * v0 + v1 * v1;
#pragma unroll
            for (int off = 1; off < 16; off <<= 1) {
                s  += __shfl_xor(s, off, 16);
                s2 += __shfl_xor(s2, off, 16);
            }
            if (l16 == 0) {
                int row = mf * 16 + lk * 4 + rr;
                atomicAdd(&sm_s[row], s);
                atomicAdd(&sm_s2[row], s2);
            }
        }
    __syncthreads();                                        // S6
    if (tid < BM) {
        float mu = sm_s[tid] * (1.f / 128.f);
        float var = sm_s2[tid] * (1.f / 128.f) - mu * mu;
        sm_mu[tid] = mu;
        sm_rs[tid] = rsqrtf(var + EPSLN);
    }
    __syncthreads();                                        // S7 (LAST barrier)

    // ---- store e_new (non-temporal stream) ----
    {
        float ge[2]  = { ld<F32>(g_e, colbase + l16),  ld<F32>(g_e, colbase + 16 + l16) };
        float bte[2] = { ld<F32>(bt_e, colbase + l16), ld<F32>(bt_e, colbase + 16 + l16) };
#pragma unroll
        for (int mf = 0; mf < 4; ++mf)
#pragma unroll
            for (int nf = 0; nf < 2; ++nf) {
                int col = colbase + nf * 16 + l16;
#pragma unroll
                for (int rr = 0; rr < 4; ++rr) {
                    int row = mf * 16 + lk * 4 + rr;
                    int eid = base + row;
                    float o = (xv[mf][nf][rr] - sm_mu[row]) * sm_rs[row] * ge[nf] + bte[nf];
                    if (eid < ne) st_nt<F32>(out, obase + (size_t)eid * 128 + col, o);
                }
            }
    }

    // ---- packed-bf16 atomic scatter: lane -> col pair; 1 instr covers a row ----
    {
        int col2 = (tid & 63) * 2;          // even column
        int r0 = (tid >> 6) * 16;           // 4 groups x 16 rows
        for (int rr = 0; rr < 16; ++rr) {
            int row = r0 + rr;
            int eid = base + row;
            if (eid < ne) {
                uint32_t m2 = *(const uint32_t*)(xs + xaddr(row, 128 + col2));
                atomic_pk_add_bf16(agg + (size_t)didx[row] * 128 + col2, m2);
            }
        }
    }
}
__global__ void __launch_bounds__(256, 3) edge_mega_kernel(
    const int* __restrict__ flag,
    const void* e, const int* src, const int* dst,
    const unsigned short* p_src, const unsigned short* p_dst, const unsigned short* p_msg,
    const unsigned short* wtg, const unsigned short* wt1, const unsigned short* wt2,
    const void* b_eg, const void* b_e1, const void* b_e2,
    const void* g_e, const void* bt_e,
    unsigned short* agg, void* out, size_t obase, int ne)
{
    __shared__ short xs_raw[BM * 384];
    __shared__ int sidx[BM], didx[BM];
    __shared__ float sm_s[BM], sm_s2[BM], sm_mu[BM], sm_rs[BM];
    __shared__ float bge_s[128];
    char* xs = (char*)xs_raw;
    if (*flag) edge_mega_body<1>(xs, sidx, didx, sm_s, sm_s2, sm_mu, sm_rs, bge_s,
                                 e, src, dst, p_src, p_dst, p_msg, wtg, wt1, wt2,
                                 b_eg, b_e1, b_e2, g_e, bt_e, agg, out, obase, ne);
    else       edge_mega_body<0>(xs, sidx, didx, sm_s, sm_s2, sm_mu, sm_rs, bge_s,
                                 e, src, dst, p_src, p_dst, p_msg, wtg, wt1, wt2,
                                 b_eg, b_e1, b_e2, g_e, bt_e, agg, out, obase, ne);
}

// ---------------------------------------------------------------------------
// node update — MFMA; agg bf16; h_new stored non-temporal
// ---------------------------------------------------------------------------
template<int F32>
__device__ void node_update_body(
    char* xs, float* sm_s, float* sm_s2, float* sm_mu, float* sm_rs,
    const void* h, const unsigned short* __restrict__ agg,
    const unsigned short* __restrict__ wn1t, const unsigned short* __restrict__ wn2t,
    const void* b_n1, const void* b_n2,
    const void* g_n, const void* bt_n, void* out, int n)
{
    const int tid = threadIdx.x;
    const int base = blockIdx.x * BM;

    if (tid < BM) { sm_s[tid] = 0.f; sm_s2[tid] = 0.f; }

    for (int idx = tid; idx < BM * 32; idx += 256) {
        int r = idx >> 5, kc = (idx & 31) * 8;
        int row = base + r;
        short8 pk;
        if (row < n) {
            if (kc < 128) {
                float v[8];
                load8<F32>(h, (size_t)row * 128 + kc, v);
#pragma unroll
                for (int j = 0; j < 8; ++j) pk[j] = (short)f2bfb(v[j]);
            } else {
                pk = *(const short8*)(agg + (size_t)row * 128 + (kc - 128));
            }
        } else {
#pragma unroll
            for (int j = 0; j < 8; ++j) pk[j] = 0;
        }
        *(short8*)(xs + x2addr(r, kc)) = pk;
    }
    __syncthreads();

    const int lane = tid & 63;
    const int wv = tid >> 6;
    const int l16 = lane & 15;
    const int lk = lane >> 4;
    const int colbase = wv * 32;

    f32x4 acc1[4][2];
#pragma unroll
    for (int mf = 0; mf < 4; ++mf)
#pragma unroll
        for (int nf = 0; nf < 2; ++nf) acc1[mf][nf] = (f32x4){0.f,0.f,0.f,0.f};

    for (int kt = 0; kt < 8; ++kt) {
        int k0 = kt * 32;
        short8 a[4];
#pragma unroll
        for (int mf = 0; mf < 4; ++mf)
            a[mf] = *(const short8*)(xs + x2addr(mf * 16 + l16, k0 + lk * 8));
        short8 b0 = *(const short8*)(wn1t + ((size_t)(colbase + l16)      * 256 + k0 + lk * 8));
        short8 b1 = *(const short8*)(wn1t + ((size_t)(colbase + 16 + l16) * 256 + k0 + lk * 8));
#pragma unroll
        for (int mf = 0; mf < 4; ++mf) {
            acc1[mf][0] = __builtin_amdgcn_mfma_f32_16x16x32_bf16(a[mf], b0, acc1[mf][0], 0, 0, 0);
            acc1[mf][1] = __builtin_amdgcn_mfma_f32_16x16x32_bf16(a[mf], b1, acc1[mf][1], 0, 0, 0);
        }
    }
    __syncthreads();

    {
        float b1v[2] = { ld<F32>(b_n1, colbase + l16), ld<F32>(b_n1, colbase + 16 + l16) };
#pragma unroll
        for (int mf = 0; mf < 4; ++mf)
#pragma unroll
            for (int nf = 0; nf < 2; ++nf) {
                int col = colbase + nf * 16 + l16;
#pragma unroll
                for (int rr = 0; rr < 4; ++rr) {
                    int row = mf * 16 + lk * 4 + rr;
                    float u = acc1[mf][nf][rr] + b1v[nf];
                    u = u * sigm(u);
                    *(unsigned short*)(xs + x2addr(row, 128 + col)) = f2bfb(u);
                }
            }
    }
    __syncthreads();

    f32x4 acc2[4][2];
#pragma unroll
    for (int mf = 0; mf < 4; ++mf)
#pragma unroll
        for (int nf = 0; nf < 2; ++nf) acc2[mf][nf] = (f32x4){0.f,0.f,0.f,0.f};

    for (int kt = 0; kt < 4; ++kt) {
        int k0 = kt * 32;
        short8 a[4];
#pragma unroll
        for (int mf = 0; mf < 4; ++mf)
            a[mf] = *(const short8*)(xs + x2addr(mf * 16 + l16, 128 + k0 + lk * 8));
        short8 b0 = *(const short8*)(wn2t + ((size_t)(colbase + l16)      * 128 + k0 + lk * 8));
        short8 b1 = *(const short8*)(wn2t + ((size_t)(colbase + 16 + l16) * 128 + k0 + lk * 8));
#pragma unroll
        for (int mf = 0; mf < 4; ++mf) {
            acc2[mf][0] = __builtin_amdgcn_mfma_f32_16x16x32_bf16(a[mf], b0, acc2[mf][0], 0, 0, 0);
            acc2[mf][1] = __builtin_amdgcn_mfma_f32_16x16x32_bf16(a[mf], b1, acc2[mf][1], 0, 0, 0);
        }
    }

    float xv[4][2][4];
    {
        float b2v[2] = { ld<F32>(b_n2, colbase + l16), ld<F32>(b_n2, colbase + 16 + l16) };
#pragma unroll
        for (int mf = 0; mf < 4; ++mf)
#pragma unroll
            for (int nf = 0; nf < 2; ++nf) {
                int col = colbase + nf * 16 + l16;
#pragma unroll
                for (int rr = 0; rr < 4; ++rr) {
                    int row = mf * 16 + lk * 4 + rr;
                    unsigned short hb = *(const unsigned short*)(xs + x2addr(row, col));
                    xv[mf][nf][rr] = bfb2f(hb) + acc2[mf][nf][rr] + b2v[nf];
                }
            }
    }
#pragma unroll
    for (int mf = 0; mf < 4; ++mf)
#pragma unroll
        for (int rr = 0; rr < 4; ++rr) {
            float v0 = xv[mf][0][rr], v1 = xv[mf][1][rr];
            float s = v0 + v1;
            float s2 = v0 * v0 + v1 * v1;
#pragma unroll
            for (int off = 1; off < 16; off <<= 1) {
                s  += __shfl_xor(s, off, 16);
                s2 += __shfl_xor(s2, off, 16);
            }
            if (l16 == 0) {
                int row = mf * 16 + lk * 4 + rr;
                atomicAdd(&sm_s[row], s);
                atomicAdd(&sm_s2[row], s2);
            }
        }
    __syncthreads();
    if (tid < BM) {
        float mu = sm_s[tid] * (1.f / 128.f);
        float var = sm_s2[tid] * (1.f / 128.f) - mu * mu;
        sm_mu[tid] = mu;
        sm_rs[tid] = rsqrtf(var + EPSLN);
    }
    __syncthreads();
    {
        float gn[2]  = { ld<F32>(g_n, colbase + l16),  ld<F32>(g_n, colbase + 16 + l16) };
        float btn[2] = { ld<F32>(bt_n, colbase + l16), ld<F32>(bt_n, colbase + 16 + l16) };
#pragma unroll
        for (int mf = 0; mf < 4; ++mf)
#pragma unroll
            for (int nf = 0; nf < 2; ++nf) {
                int col = colbase + nf * 16 + l16;
#pragma unroll
                for (int rr = 0; rr < 4; ++rr) {
                    int row = mf * 16 + lk * 4 + rr;
                    float o = (xv[mf][nf][rr] - sm_mu[row]) * sm_rs[row] * gn[nf] + btn[nf];
                    if (base + row < n)
                        st_nt<F32>(out, (size_t)(base + row) * 128 + col, o);
                }
            }
    }
}
__global__ void __launch_bounds__(256, 4) node_update_kernel(
    const int* __restrict__ flag,
    const void* h, const unsigned short* agg,
    const unsigned short* wn1t, const unsigned short* wn2t,
    const void* b_n1, const void* b_n2,
    const void* g_n, const void* bt_n, void* out, int n)
{
    __shared__ short x2_raw[BM * 256];   // 32 KB
    __shared__ float sm_s[BM], sm_s2[BM], sm_mu[BM], sm_rs[BM];
    char* xs = (char*)x2_raw;
    if (*flag) node_update_body<1>(xs, sm_s, sm_s2, sm_mu, sm_rs, h, agg, wn1t, wn2t,
                                   b_n1, b_n2, g_n, bt_n, out, n);
    else       node_update_body<0>(xs, sm_s, sm_s2, sm_mu, sm_rs, h, agg, wn1t, wn2t,
                                   b_n1, b_n2, g_n, bt_n, out, n);
}

// ---------------------------------------------------------------------------
extern "C" void kernel_launch(void* const* d_in, const int* in_sizes, int n_in,
                              void* d_out, int out_size, void* d_ws, size_t ws_size,
                              hipStream_t stream)
{
    const void* h     = d_in[0];
    const void* e     = d_in[1];
    const int*  src   = (const int*)d_in[2];
    const int*  dst   = (const int*)d_in[3];
    const void* w_src = d_in[4];
    const void* b_src = d_in[5];
    const void* w_dst = d_in[6];
    const void* b_dst = d_in[7];
    const void* w_eg  = d_in[8];
    const void* b_eg  = d_in[9];
    const void* w_msg = d_in[10];
    const void* b_msg = d_in[11];
    const void* w_n1  = d_in[12];
    const void* b_n1  = d_in[13];
    const void* w_n2  = d_in[14];
    const void* b_n2  = d_in[15];
    const void* w_e1  = d_in[16];
    const void* b_e1  = d_in[17];
    const void* w_e2  = d_in[18];
    const void* b_e2  = d_in[19];
    const void* g_n   = d_in[20];
    const void* bt_n  = d_in[21];
    const void* g_e   = d_in[22];
    const void* bt_e  = d_in[23];

    const int n  = in_sizes[0] / DIMN;   // 40000
    const int ne = in_sizes[1] / DIMN;   // 640000

    char* ws = (char*)d_ws;
    unsigned short* p_src = (unsigned short*)ws;       ws += (size_t)n * DIMN * 2;
    unsigned short* p_dst = (unsigned short*)ws;       ws += (size_t)n * DIMN * 2;
    unsigned short* p_msg = (unsigned short*)ws;       ws += (size_t)n * DIMN * 2;
    unsigned short* agg   = (unsigned short*)ws;       ws += (size_t)n * DIMN * 2;
    int*   flag  = (int*)ws;                           ws += 256;
    unsigned short* wtg  = (unsigned short*)ws;        ws += 128 * 128 * 2;
    unsigned short* wt2  = (unsigned short*)ws;        ws += 128 * 128 * 2;
    unsigned short* wt1  = (unsigned short*)ws;        ws += 128 * 384 * 2;
    unsigned short* wts  = (unsigned short*)ws;        ws += 128 * 128 * 2;
    unsigned short* wtd  = (unsigned short*)ws;        ws += 128 * 128 * 2;
    unsigned short* wtm  = (unsigned short*)ws;        ws += 128 * 128 * 2;
    unsigned short* wn1t = (unsigned short*)ws;        ws += 128 * 256 * 2;
    unsigned short* wn2t = (unsigned short*)ws;        ws += 128 * 128 * 2;

    hipMemsetAsync(agg, 0, (size_t)n * DIMN * sizeof(unsigned short), stream);

    detect_dtype_kernel<<<1, 64, 0, stream>>>((const uint32_t*)h, flag);

    prep_weights_kernel<<<704, 256, 0, stream>>>(
        flag, w_eg, w_e1, w_e2, w_src, w_dst, w_msg, w_n1, w_n2,
        wtg, wt1, wt2, wts, wtd, wtm, wn1t, wn2t);

    int nb_n = (n + BM - 1) / BM;
    int nb_e = (ne + BM - 1) / BM;

    node_proj_kernel<<<nb_n, 256, 0, stream>>>(
        flag, h, wts, wtd, wtm, b_src, b_dst, b_msg, p_src, p_dst, p_msg, n);

    edge_mega_kernel<<<nb_e, 256, 0, stream>>>(
        flag, e, src, dst, p_src, p_dst, p_msg, wtg, wt1, wt2,
        b_eg, b_e1, b_e2, g_e, bt_e, agg, d_out, (size_t)n * DIMN, ne);

    node_update_kernel<<<nb_n, 256, 0, stream>>>(
        flag, h, agg, wn1t, wn2t, b_n1, b_n2, g_n, bt_n, d_out, n);
}